// Round 2
// baseline (6243.153 us; speedup 1.0000x reference)
//
#include <hip/hip_runtime.h>
#include <stdint.h>

#define Bn  128
#define En  1024
#define Kn  64
#define HDn 256
#define NGc 8    // batch groups of 16 rows
#define NHc 4    // WGs (quarters) per group, 4 waves each
#define NWc 4    // waves per WG

typedef short s8v __attribute__((ext_vector_type(8)));   // 8 x bf16 (bits)
typedef float f4v __attribute__((ext_vector_type(4)));

static __device__ __forceinline__ unsigned short f2bf(float f) {
  union { float f; unsigned u; } cv; cv.f = f;
  unsigned u = cv.u;
  unsigned r = u + 0x7fffu + ((u >> 16) & 1u);   // round-nearest-even
  return (unsigned short)(r >> 16);
}
static __device__ __forceinline__ float sigm(float x) {
  return 1.0f / (1.0f + __expf(-x));
}

// ---- prologue 1: detect mask storage format (1-byte bool vs 4-byte word) ----
__global__ void detect_mask_fmt(const uint8_t* __restrict__ m8, int* __restrict__ fmt) {
  const int b = blockIdx.x;
  const int e0 = threadIdx.x * 4;
  const uint8_t* row = m8 + (size_t)b * En;
  int bad = 0;
  uint8_t prev = row[e0];
  #pragma unroll
  for (int i = 1; i <= 4; ++i) {
    int e = e0 + i;
    if (e < En) {
      uint8_t cur = row[e];
      if (prev == 0 && cur != 0) bad = 1;
      prev = cur;
    }
  }
  if (threadIdx.x == 0 && row[0] == 0) bad = 1;
  if (bad) atomicOr(fmt, 1);
}

// ---- prologue 2: seq is one-hot -> recover event index via ballot ----
__global__ void compute_ev(const float* __restrict__ seq, int* __restrict__ ev) {
  const int idx  = blockIdx.x * 4 + (threadIdx.x >> 6);  // flat (b*En + t)
  const int lane = threadIdx.x & 63;
  float v = seq[(size_t)idx * Kn + lane];
  unsigned long long m = __ballot(v > 0.5f);
  if (lane == 0) ev[idx] = __ffsll((long long)m) - 1;
}

// ---- prologue 3: transpose U into gate-major gather table ----
// Ut[(k*HDn + j)*8 + g7] = U_w[(g7*HDn + j)*Kn + k], pad g7=7 with 0.
// 512 KB, L2-resident; replaces the 48 KB per-WG LDS copy.
__global__ void make_ut(const float* __restrict__ U_w, float* __restrict__ Ut) {
  const int k = blockIdx.x;        // 64
  const int j = threadIdx.x;       // 256
  float* dst = Ut + ((size_t)k * HDn + j) * 8;
  #pragma unroll
  for (int g7 = 0; g7 < 7; ++g7)
    dst[g7] = U_w[((size_t)g7 * HDn + j) * Kn + k];
  dst[7] = 0.0f;
}

// ---- main: 8 groups x 4 WGs x 4 waves; V-slice in registers per wave ----
// Own 64-dim quarter of h exchanged via LDS (barrier-synced); the other 3
// quarters via coherent global. One relaxed flag STORE per WG per step (no
// atomic RMW -> no 16-way MALL serialization); consumers poll 3 peer flags
// with a prefetched short-circuit so the poll does not drain the HBM output
// store queue (in-order vmcnt).
__global__ __launch_bounds__(256, 1) void ct_main(
    const float* __restrict__ times, const uint8_t* __restrict__ mask8,
    const float* __restrict__ Ut,   const float* __restrict__ U_b,
    const float* __restrict__ V_w,  const float* __restrict__ V_b,
    const float* __restrict__ Lw,   const float* __restrict__ scale,
    const int* __restrict__ ev,     unsigned short* __restrict__ h_buf,
    int* __restrict__ ctr,          const int* __restrict__ fmtp,
    float* __restrict__ out_lam, float* __restrict__ out_cl,
    float* __restrict__ out_cb,  float* __restrict__ out_dl,
    float* __restrict__ out_og)
{
  // own-quarter h ping-pong: [parity][m=16][d_local=64] bf16, XOR-swizzled
  __shared__ unsigned short h_lds[2][16 * 64];   // 4 KB

  const int tid  = threadIdx.x;
  const int lane = tid & 63;
  const int wv   = tid >> 6;        // wave index = slice within WG quarter
  const int col  = lane & 15;       // B/C column: dim for gate tiles
  const int quad = lane >> 4;
  const int g    = blockIdx.x & 7;  // batch group (same XCD for all 4 WGs)
  const int hh   = blockIdx.x >> 3; // quarter index 0..3
  const int s    = hh * NWc + wv;   // absolute 16-dim slice 0..15
  const int d0   = s * 16;
  const int fmt  = *fmtp;

  // zero both LDS parities (t=0 reads parity 0)
  for (int i = tid; i < 2 * 16 * 64; i += 256) h_lds[0][i] = 0;
  __syncthreads();

  // ---- V-slice B-fragments pinned in registers (bf16) ----
  // B-operand layout: lane holds B[n=lane&15][k = kc*32 + quad*8 + j], j=0..7
  s8v Bv[7][8];
  #pragma unroll
  for (int g7 = 0; g7 < 7; ++g7) {
    const float* src = V_w + (size_t)(g7 * HDn + d0 + col) * HDn;
    #pragma unroll
    for (int kc = 0; kc < 8; ++kc) {
      const float* p = src + kc * 32 + quad * 8;
      f4v a = *(const f4v*)(p);
      f4v b = *(const f4v*)(p + 4);
      s8v fr;
      fr[0] = (short)f2bf(a[0]); fr[1] = (short)f2bf(a[1]);
      fr[2] = (short)f2bf(a[2]); fr[3] = (short)f2bf(a[3]);
      fr[4] = (short)f2bf(b[0]); fr[5] = (short)f2bf(b[1]);
      fr[6] = (short)f2bf(b[2]); fr[7] = (short)f2bf(b[3]);
      Bv[g7][kc] = fr;
    }
  }
  // lambda tile: cols 0..3 hold Lw rows [4s,4s+4), rest zero
  s8v BL[8];
  const int kkc = s * 4 + col;
  {
    const bool lv = (col < 4);
    const float* src = Lw + (size_t)(lv ? kkc : 0) * HDn;
    #pragma unroll
    for (int kc = 0; kc < 8; ++kc) {
      const float* p = src + kc * 32 + quad * 8;
      s8v fr;
      #pragma unroll
      for (int j = 0; j < 8; ++j) fr[j] = lv ? (short)f2bf(p[j]) : (short)0;
      BL[kc] = fr;
    }
  }
  float bias[7];
  #pragma unroll
  for (int g7 = 0; g7 < 7; ++g7) {
    int j = g7 * HDn + d0 + col;
    bias[g7] = U_b[j] + V_b[j];
  }
  const float sc = scale[(kkc < Kn) ? kkc : 0];

  unsigned int* hbuf32 = (unsigned int*)h_buf;

  // flags: slot (hh*8+g), 128 B apart; value = steps published
  int* flag_my = ctr + (hh * 8 + g) * 32;
  int* flag_p0 = ctr + ((((hh + 1) & 3) * 8) + g) * 32;
  int* flag_p1 = ctr + ((((hh + 2) & 3) * 8) + g) * 32;
  int* flag_p2 = ctr + ((((hh + 3) & 3) * 8) + g) * 32;
  int p0 = 0, p1 = 0, p2 = 0;   // prefetched flag values

  float c[4]  = {0, 0, 0, 0}, cb[4] = {0, 0, 0, 0};
  float hreg[4] = {0, 0, 0, 0}, pm[4] = {0, 0, 0, 0};

  #pragma unroll 1
  for (int t = 0; t <= En; ++t) {
    const bool has_main = (t < En);

    // per-step independent loads (ev/dt/mask + U gather, all L2-resident)
    int evv[4]; float dtv[4], mk[4];
    f4v u0v[4], u1v[4];
    if (has_main) {
      #pragma unroll
      for (int r = 0; r < 4; ++r) {
        const int bglob = g * 16 + quad * 4 + r;
        evv[r] = ev[(size_t)bglob * En + t];
        const float* tp = times + (size_t)bglob * (En + 1) + t;
        dtv[r] = tp[1] - tp[0];
        int mraw;
        if (fmt) mraw = ((const int*)mask8)[(size_t)bglob * En + t];
        else     mraw = (int)mask8[(size_t)bglob * En + t];
        mk[r] = (mraw != 0) ? 1.0f : 0.0f;
      }
      #pragma unroll
      for (int r = 0; r < 4; ++r) {
        const float* up = Ut + ((size_t)evv[r] * HDn + d0 + col) * 8;
        u0v[r] = *(const f4v*)(up);
        u1v[r] = *(const f4v*)(up + 4);
      }
    }

    float pmo[4];
    #pragma unroll
    for (int r = 0; r < 4; ++r) pmo[r] = pm[r];

    // wait for the 3 peer WGs to have published step t-1 (flag >= t).
    // Prefetched p0..p2 usually satisfy this without touching the (store-
    // laden) vmcnt queue; the poll loop is the slow path.
    if (t > 0) {
      if (p0 < t || p1 < t || p2 < t) {
        for (;;) {
          p0 = __hip_atomic_load(flag_p0, __ATOMIC_RELAXED, __HIP_MEMORY_SCOPE_AGENT);
          p1 = __hip_atomic_load(flag_p1, __ATOMIC_RELAXED, __HIP_MEMORY_SCOPE_AGENT);
          p2 = __hip_atomic_load(flag_p2, __ATOMIC_RELAXED, __HIP_MEMORY_SCOPE_AGENT);
          if (p0 >= t && p1 >= t && p2 >= t) break;
          __builtin_amdgcn_s_sleep(1);
        }
      }
      // pin subsequent h-loads below the observed flags (rule #18)
      __builtin_amdgcn_sched_barrier(0);
      asm volatile("" ::: "memory");
    }

    // ---- A-fragments: lane holds A[m=lane&15][k = kc*32 + quad*8 + j] ----
    const int par = t & 1;
    const unsigned long long* hb64 =
        (const unsigned long long*)(h_buf + (size_t)(par * NGc + g) * 4096);
    const char* lbase_r = (const char*)&h_lds[par][0];
    s8v A[8];
    // peer quarters first: coherent global u64 loads (long latency, issue early)
    #pragma unroll
    for (int kc = 0; kc < 8; ++kc) {
      if ((kc >> 1) != hh) {
        const int sp = kc * 2 + (quad >> 1);
        const unsigned long long* q = hb64 + sp * 64 + col * 4 + (quad & 1) * 2;
        union { unsigned long long q[2]; s8v v; } u;
        u.q[0] = __hip_atomic_load(q + 0, __ATOMIC_RELAXED, __HIP_MEMORY_SCOPE_AGENT);
        u.q[1] = __hip_atomic_load(q + 1, __ATOMIC_RELAXED, __HIP_MEMORY_SCOPE_AGENT);
        A[kc] = u.v;
      }
    }
    // own quarter from LDS (swizzled ds_read_b128, 2-way max conflict)
    #pragma unroll
    for (int kc = 0; kc < 8; ++kc) {
      if ((kc >> 1) == hh) {
        const int kcl = kc & 1;
        const unsigned boff =
            (unsigned)(col * 128 + kcl * 64 + quad * 16) ^ ((unsigned)(col & 7) << 4);
        A[kc] = *(const s8v*)(lbase_r + boff);
      }
    }

    // ---- MFMA (kc order 0..7 preserved -> bit-identical accumulation) ----
    f4v acc[7] = {}; f4v accL = {0.0f, 0.0f, 0.0f, 0.0f};
    if (has_main) {
      #pragma unroll
      for (int kc = 0; kc < 8; ++kc) {
        #pragma unroll
        for (int g7 = 0; g7 < 7; ++g7)
          acc[g7] = __builtin_amdgcn_mfma_f32_16x16x32_bf16(A[kc], Bv[g7][kc], acc[g7], 0, 0, 0);
      }
    }
    #pragma unroll
    for (int kc = 0; kc < 8; ++kc)
      accL = __builtin_amdgcn_mfma_f32_16x16x32_bf16(A[kc], BL[kc], accL, 0, 0, 0);

    float clv[4], cbv[4], dlv[4], ogv[4];
    if (has_main) {
      #pragma unroll
      for (int r = 0; r < 4; ++r) {
        float nn0 = acc[0][r] + u0v[r][0] + bias[0];
        float nn1 = acc[1][r] + u0v[r][1] + bias[1];
        float nn2 = acc[2][r] + u0v[r][2] + bias[2];
        float nn3 = acc[3][r] + u0v[r][3] + bias[3];
        float nn4 = acc[4][r] + u1v[r][0] + bias[4];
        float nn5 = acc[5][r] + u1v[r][1] + bias[5];
        float nn6 = acc[6][r] + u1v[r][2] + bias[6];
        float i_ = sigm(nn0), f_ = sigm(nn1);
        float ib = sigm(nn2), fb = sigm(nn3);
        float z_ = 2.0f * sigm(nn4), o_ = sigm(nn5);
        float dl = __logf(1.0f + __expf(nn6));          // softplus
        float clow = f_ * c[r] + i_ * z_;
        float cbn  = fb * cb[r] + ib * z_;
        float ed   = __expf(-dtv[r] * dl);
        float cn   = cbn + (clow - cbn) * ed;
        float hn   = o_ * (2.0f * sigm(2.0f * cn) - 1.0f);
        const bool mb = (mk[r] != 0.0f);
        c[r]    = mb ? cn  : c[r];
        cb[r]   = mb ? cbn : cb[r];
        hreg[r] = mb ? hn  : hreg[r];
        pm[r]   = mk[r];
        clv[r] = mb ? clow : 0.0f;
        cbv[r] = mb ? cbn  : 0.0f;
        dlv[r] = mb ? dl   : 0.0f;
        ogv[r] = mb ? o_   : 0.0f;
      }

      // ---- publish h slice: LDS (own WG) + coherent global (peers) ----
      // pack (col, col^1) bf16 pairs into dwords via neighbor exchange;
      // even cols store rows {0,1} of their quad, odd cols rows {2,3}.
      const int par2 = (t + 1) & 1;
      float hsw[4];
      #pragma unroll
      for (int r = 0; r < 4; ++r) hsw[r] = __shfl_xor(hreg[r], 1, 64);
      const int evn = (col & 1);
      unsigned int w[4];
      #pragma unroll
      for (int r = 0; r < 4; ++r) {
        unsigned int a  = f2bf(hreg[r]);
        unsigned int bn = f2bf(hsw[r]);
        w[r] = evn ? (bn | (a << 16)) : (a | (bn << 16));   // low = even col
      }
      const unsigned int wa = evn ? w[2] : w[0];
      const unsigned int wb = evn ? w[3] : w[1];
      const int ra    = evn ? 2 : 0;
      const int row_a = quad * 4 + ra;
      const int row_b = row_a + 1;
      // LDS mirror (swizzled dword writes)
      char* lbase_w = (char*)&h_lds[par2][0];
      const unsigned xa =
          (unsigned)(row_a * 128 + (wv * 16 + (col & ~1)) * 2) ^ ((unsigned)(row_a & 7) << 4);
      const unsigned xb =
          (unsigned)(row_b * 128 + (wv * 16 + (col & ~1)) * 2) ^ ((unsigned)(row_b & 7) << 4);
      *(unsigned int*)(lbase_w + xa) = wa;
      *(unsigned int*)(lbase_w + xb) = wb;
      // global copy for the 3 peer WGs
      unsigned int* hw32 = hbuf32 + (size_t)(par2 * NGc + g) * 2048 + s * 128;
      __hip_atomic_store(hw32 + row_a * 8 + (col >> 1), wa,
                         __ATOMIC_RELAXED, __HIP_MEMORY_SCOPE_AGENT);
      __hip_atomic_store(hw32 + row_b * 8 + (col >> 1), wb,
                         __ATOMIC_RELAXED, __HIP_MEMORY_SCOPE_AGENT);
      // __syncthreads lowers to s_waitcnt vmcnt(0) lgkmcnt(0) + s_barrier:
      // drains the h stores to the coherence point for ALL 4 waves, orders
      // the LDS mirror, and only then wave 0 raises the flag.
      __syncthreads();
      if (tid == 0)
        __hip_atomic_store(flag_my, t + 1, __ATOMIC_RELAXED, __HIP_MEMORY_SCOPE_AGENT);
      // prefetch peer flags for step t+1 BEFORE the output stores: checking
      // them next iteration costs vmcnt(N), not a store-queue drain.
      p0 = __hip_atomic_load(flag_p0, __ATOMIC_RELAXED, __HIP_MEMORY_SCOPE_AGENT);
      p1 = __hip_atomic_load(flag_p1, __ATOMIC_RELAXED, __HIP_MEMORY_SCOPE_AGENT);
      p2 = __hip_atomic_load(flag_p2, __ATOMIC_RELAXED, __HIP_MEMORY_SCOPE_AGENT);
    }

    // lambda epilogue for step t-1 — off the critical path (after flag)
    if (t > 0 && col < 4) {
      #pragma unroll
      for (int r = 0; r < 4; ++r) {
        const int bglob = g * 16 + quad * 4 + r;
        float q   = accL[r] / sc;
        float lam = sc * __logf(1.0f + __expf(q));
        __builtin_nontemporal_store((pmo[r] != 0.0f) ? lam : 0.0f,
            &out_lam[((size_t)bglob * En + (t - 1)) * Kn + kkc]);
      }
    }

    // bulk output stores (drain overlaps the next step's A-load latency)
    if (has_main) {
      #pragma unroll
      for (int r = 0; r < 4; ++r) {
        const size_t off =
            ((size_t)(g * 16 + quad * 4 + r) * En + t) * HDn + d0 + col;
        __builtin_nontemporal_store(clv[r], &out_cl[off]);
        __builtin_nontemporal_store(cbv[r], &out_cb[off]);
        __builtin_nontemporal_store(dlv[r], &out_dl[off]);
        __builtin_nontemporal_store(ogv[r], &out_og[off]);
      }
    }
  }
}

extern "C" void kernel_launch(void* const* d_in, const int* in_sizes, int n_in,
                              void* d_out, int out_size, void* d_ws, size_t ws_size,
                              hipStream_t stream) {
  const float*   seq   = (const float*)d_in[0];
  const uint8_t* mask  = (const uint8_t*)d_in[1];
  const float*   times = (const float*)d_in[2];
  const float*   U_w   = (const float*)d_in[3];
  const float*   U_b   = (const float*)d_in[4];
  const float*   V_w   = (const float*)d_in[5];
  const float*   V_b   = (const float*)d_in[6];
  const float*   Lw    = (const float*)d_in[7];
  const float*   scale = (const float*)d_in[8];

  char* ws = (char*)d_ws;
  unsigned short* h_buf = (unsigned short*)ws;        // 131072 B
  int* ctr  = (int*)(ws + 131072);                    // 32 slots x 128 B = 4096
  int* fmt  = (int*)(ws + 135168);                    // 128 B
  float* Ut = (float*)(ws + 135296);                  // 64*256*8*4 = 524288 B
  int* ev   = (int*)(ws + 659584);                    // 128*1024*4 = 524288 B

  // zero h ping-pong, flags, fmt (Ut/ev fully overwritten)
  hipMemsetAsync(d_ws, 0, 135296, stream);

  detect_mask_fmt<<<dim3(Bn), dim3(256), 0, stream>>>(mask, fmt);
  compute_ev<<<dim3(Bn * En / 4), dim3(256), 0, stream>>>(seq, ev);
  make_ut<<<dim3(Kn), dim3(HDn), 0, stream>>>(U_w, Ut);

  float* out = (float*)d_out;
  float* out_lam = out;
  float* out_cl  = out_lam + (size_t)Bn * En * Kn;
  float* out_cb  = out_cl  + (size_t)Bn * En * HDn;
  float* out_dl  = out_cb  + (size_t)Bn * En * HDn;
  float* out_og  = out_dl  + (size_t)Bn * En * HDn;

  ct_main<<<dim3(NGc * NHc), dim3(64 * NWc), 0, stream>>>(
      times, mask, Ut, U_b, V_w, V_b, Lw, scale,
      ev, h_buf, ctr, fmt, out_lam, out_cl, out_cb, out_dl, out_og);
}